// Round 4
// baseline (2356.700 us; speedup 1.0000x reference)
//
#include <hip/hip_runtime.h>

// GCN, bucketed-LDS pipeline:
//   bucket = 256 consecutive dst nodes (NBUCK = ceil(N/256) <= 512)
//   k_hist:     per-bucket edge counts (LDS hist, few global atomics)
//   k_scanb:    exclusive scan -> bbase[], gcur[]
//   k_binA:     tile-wise LDS counting sort by bucket -> binned[] (packed
//               src | dstlo<<17), dumped as contiguous per-bucket runs
//   k_nodedeg:  per-bucket dstlo histogram -> dinv = rsqrt(deg+1)
//   k_gemm:     hs = (X @ W) * dinv[row]   (W in LDS, thread-per-row)
//   k_aggf<F>:  per-bucket: LDS fp32 accumulator [256 x F]; stream edges,
//               gather hs[src] rows, ds_add; epilogue: self-loop+bias+relu
//   k_classifier: 32->10 + log_softmax

#define BSHIFT 8
#define BMASK 255
#define NBUCK_MAX 512
#define TILE 8192          // edges per binA tile
#define EPT 32             // edges per thread (TILE / 256)

__global__ void k_hist(const int* __restrict__ dst, int* __restrict__ bcnt, int E) {
    __shared__ int h[NBUCK_MAX];
    for (int i = threadIdx.x; i < NBUCK_MAX; i += blockDim.x) h[i] = 0;
    __syncthreads();
    for (int e = blockIdx.x * blockDim.x + threadIdx.x; e < E; e += gridDim.x * blockDim.x)
        atomicAdd(&h[dst[e] >> BSHIFT], 1);
    __syncthreads();
    for (int i = threadIdx.x; i < NBUCK_MAX; i += blockDim.x)
        if (h[i]) atomicAdd(&bcnt[i], h[i]);
}

// single block, 512 threads: exclusive scan of bcnt -> bbase (and gcur copy)
__global__ void k_scanb(const int* __restrict__ bcnt, int* __restrict__ bbase,
                        int* __restrict__ gcur, int E) {
    __shared__ int s[NBUCK_MAX];
    int t = threadIdx.x;
    int v = bcnt[t];
    s[t] = v;
    __syncthreads();
    for (int o = 1; o < NBUCK_MAX; o <<= 1) {
        int u = (t >= o) ? s[t - o] : 0;
        __syncthreads();
        s[t] += u;
        __syncthreads();
    }
    int ex = s[t] - v;
    bbase[t] = ex;
    gcur[t] = ex;
    if (t == NBUCK_MAX - 1) bbase[NBUCK_MAX] = E;
}

// Tile-wise LDS counting sort by bucket; dump contiguous per-bucket runs.
__global__ __launch_bounds__(256) void k_binA(const int* __restrict__ src,
                                              const int* __restrict__ dst,
                                              int* __restrict__ gcur,
                                              int* __restrict__ binned, int E) {
    __shared__ int hist[NBUCK_MAX];
    __shared__ int lbase[NBUCK_MAX];
    __shared__ int gdelta[NBUCK_MAX];
    __shared__ int cnt2[NBUCK_MAX];
    __shared__ int scanb[256];
    __shared__ int stage[TILE];
    __shared__ unsigned short sbucket[TILE];

    int t = threadIdx.x;
    for (int i = t; i < NBUCK_MAX; i += 256) { hist[i] = 0; cnt2[i] = 0; }
    __syncthreads();

    int tileStart = blockIdx.x * TILE;
    int cntTile = min(TILE, E - tileStart);

    int vals[EPT];
    int bks[EPT];
#pragma unroll
    for (int i = 0; i < EPT; i++) {
        int e = tileStart + t + i * 256;
        if (e < E) {
            int s = src[e], d = dst[e];
            vals[i] = s | ((d & BMASK) << 17);
            bks[i] = d >> BSHIFT;
            atomicAdd(&hist[bks[i]], 1);
        } else bks[i] = -1;
    }
    __syncthreads();

    // exclusive scan of hist[512] with 256 threads (pairs)
    int a0 = hist[2 * t], a1 = hist[2 * t + 1];
    int ts = a0 + a1;
    scanb[t] = ts;
    __syncthreads();
    for (int o = 1; o < 256; o <<= 1) {
        int u = (t >= o) ? scanb[t - o] : 0;
        __syncthreads();
        scanb[t] += u;
        __syncthreads();
    }
    int ex = scanb[t] - ts;
    lbase[2 * t] = ex;
    lbase[2 * t + 1] = ex + a0;
    __syncthreads();

    // reserve global space per bucket
    for (int b = t; b < NBUCK_MAX; b += 256) {
        int c = hist[b];
        int g = c ? atomicAdd(&gcur[b], c) : 0;
        gdelta[b] = g - lbase[b];
    }
    // placement into stage
#pragma unroll
    for (int i = 0; i < EPT; i++) {
        if (bks[i] >= 0) {
            int r = atomicAdd(&cnt2[bks[i]], 1);
            int slot = lbase[bks[i]] + r;
            stage[slot] = vals[i];
            sbucket[slot] = (unsigned short)bks[i];
        }
    }
    __syncthreads();
    // dump: contiguous runs per bucket
    for (int i = t; i < cntTile; i += 256) {
        int b = sbucket[i];
        binned[gdelta[b] + i] = stage[i];
    }
}

// Per-bucket dstlo histogram -> dinv = rsqrt(deg+1)
__global__ void k_nodedeg(const int* __restrict__ bbase, const int* __restrict__ binned,
                          float* __restrict__ dinv, int n) {
    __shared__ int cnt[256];
    int b = blockIdx.x, t = threadIdx.x;
    cnt[t] = 0;
    __syncthreads();
    int beg = bbase[b], end = bbase[b + 1];
    for (int i = beg + t; i < end; i += 256)
        atomicAdd(&cnt[(binned[i] >> 17) & BMASK], 1);
    __syncthreads();
    int g = (b << BSHIFT) + t;
    if (g < n) dinv[g] = rsqrtf((float)cnt[t] + 1.0f);
}

// H[n,M] = (X[n,K] @ W[K,M]) * dinv[row]
template<int K, int M>
__global__ void k_gemm(const float* __restrict__ X, const float* __restrict__ W,
                       const float* __restrict__ dinv, float* __restrict__ H, int n) {
    __shared__ float Ws[K * M];
    for (int i = threadIdx.x; i < K * M; i += blockDim.x) Ws[i] = W[i];
    __syncthreads();
    int r = blockIdx.x * blockDim.x + threadIdx.x;
    if (r >= n) return;
    float acc[M];
#pragma unroll
    for (int j = 0; j < M; j++) acc[j] = 0.f;
    const float* xr = X + (size_t)r * K;
    for (int k = 0; k < K; k += 4) {
        float4 xv = *(const float4*)(xr + k);
#pragma unroll
        for (int j = 0; j < M; j++) {
            acc[j] += xv.x * Ws[(k + 0) * M + j];
            acc[j] += xv.y * Ws[(k + 1) * M + j];
            acc[j] += xv.z * Ws[(k + 2) * M + j];
            acc[j] += xv.w * Ws[(k + 3) * M + j];
        }
    }
    float di = dinv[r];
    float* hr = H + (size_t)r * M;
#pragma unroll
    for (int j = 0; j < M; j += 4)
        *(float4*)(hr + j) = make_float4(acc[j] * di, acc[j + 1] * di,
                                         acc[j + 2] * di, acc[j + 3] * di);
}

// Fused bucket aggregate, F=64: one block per bucket, acc[256*64] in LDS.
__global__ __launch_bounds__(512) void k_aggf64(const int* __restrict__ bbase,
                                                const int* __restrict__ binned,
                                                const float* __restrict__ hs,
                                                const float* __restrict__ dinv,
                                                const float* __restrict__ bv,
                                                float* __restrict__ out, int n) {
    __shared__ float acc[256 * 64];
    int t = threadIdx.x;
    for (int i = t; i < 256 * 64; i += 512) acc[i] = 0.f;
    __syncthreads();
    int b = blockIdx.x, lo = b << BSHIFT;
    int beg = bbase[b], end = bbase[b + 1];
    int wave = t >> 6, lane = t & 63;
    for (int base = beg + wave * 64; base < end; base += 8 * 64) {
        int nrem = min(64, end - base);
        int v = (lane < nrem) ? binned[base + lane] : 0;
        if (nrem == 64) {
#pragma unroll 8
            for (int j = 0; j < 64; j++) {
                int u = __shfl(v, j);
                int s = u & 0x1FFFF;
                float x = hs[(size_t)s * 64 + lane];
                atomicAdd(&acc[(((u >> 17) & BMASK) << 6) + lane], x);
            }
        } else {
            for (int j = 0; j < nrem; j++) {
                int u = __shfl(v, j);
                int s = u & 0x1FFFF;
                float x = hs[(size_t)s * 64 + lane];
                atomicAdd(&acc[(((u >> 17) & BMASK) << 6) + lane], x);
            }
        }
    }
    __syncthreads();
    int nn = min(256, n - lo);
    for (int i = t; i < nn * 64; i += 512) {
        int node = i >> 6, f = i & 63;
        int g = lo + node;
        float val = (acc[i] + hs[(size_t)g * 64 + f]) * dinv[g] + bv[f];
        out[(size_t)g * 64 + f] = fmaxf(val, 0.f);
    }
}

// Fused bucket aggregate, F=32: half-wave per edge.
__global__ __launch_bounds__(512) void k_aggf32(const int* __restrict__ bbase,
                                                const int* __restrict__ binned,
                                                const float* __restrict__ hs,
                                                const float* __restrict__ dinv,
                                                const float* __restrict__ bv,
                                                float* __restrict__ out, int n) {
    __shared__ float acc[256 * 32];
    int t = threadIdx.x;
    for (int i = t; i < 256 * 32; i += 512) acc[i] = 0.f;
    __syncthreads();
    int b = blockIdx.x, lo = b << BSHIFT;
    int beg = bbase[b], end = bbase[b + 1];
    int wave = t >> 6, lane = t & 63;
    int half = lane >> 5, l5 = lane & 31;
    for (int base = beg + wave * 64; base < end; base += 8 * 64) {
        int nrem = min(64, end - base);
        int v = (lane < nrem) ? binned[base + lane] : 0;
        if (nrem == 64) {
#pragma unroll 8
            for (int jj = 0; jj < 64; jj += 2) {
                int u = __shfl(v, jj + half);
                int s = u & 0x1FFFF;
                float x = hs[(size_t)s * 32 + l5];
                atomicAdd(&acc[(((u >> 17) & BMASK) << 5) + l5], x);
            }
        } else {
            for (int jj = 0; jj < nrem; jj += 2) {
                int idx = jj + half;
                if (idx < nrem) {
                    int u = __shfl(v, idx);
                    int s = u & 0x1FFFF;
                    float x = hs[(size_t)s * 32 + l5];
                    atomicAdd(&acc[(((u >> 17) & BMASK) << 5) + l5], x);
                }
            }
        }
    }
    __syncthreads();
    int nn = min(256, n - lo);
    for (int i = t; i < nn * 32; i += 512) {
        int node = i >> 5, f = i & 31;
        int g = lo + node;
        float val = (acc[i] + hs[(size_t)g * 32 + f]) * dinv[g] + bv[f];
        out[(size_t)g * 32 + f] = fmaxf(val, 0.f);
    }
}

// logits = act2 @ Wc + bc; log_softmax
__global__ void k_classifier(const float* __restrict__ ACT, const float* __restrict__ Wc,
                             const float* __restrict__ bc, float* __restrict__ out, int n) {
    __shared__ float Wcs[32 * 10];
    __shared__ float bcs[10];
    for (int i = threadIdx.x; i < 320; i += blockDim.x) Wcs[i] = Wc[i];
    if (threadIdx.x < 10) bcs[threadIdx.x] = bc[threadIdx.x];
    __syncthreads();
    int r = blockIdx.x * blockDim.x + threadIdx.x;
    if (r >= n) return;
    const float* a = ACT + (size_t)r * 32;
    float logits[10];
#pragma unroll
    for (int c = 0; c < 10; c++) logits[c] = bcs[c];
#pragma unroll
    for (int k = 0; k < 32; k += 4) {
        float4 av = *(const float4*)(a + k);
#pragma unroll
        for (int c = 0; c < 10; c++) {
            logits[c] += av.x * Wcs[(k + 0) * 10 + c] + av.y * Wcs[(k + 1) * 10 + c]
                       + av.z * Wcs[(k + 2) * 10 + c] + av.w * Wcs[(k + 3) * 10 + c];
        }
    }
    float m = logits[0];
#pragma unroll
    for (int c = 1; c < 10; c++) m = fmaxf(m, logits[c]);
    float ssum = 0.f;
#pragma unroll
    for (int c = 0; c < 10; c++) ssum += __expf(logits[c] - m);
    float lse = m + __logf(ssum);
    float* o = out + (size_t)r * 10;
#pragma unroll
    for (int c = 0; c < 10; c++) o[c] = logits[c] - lse;
}

extern "C" void kernel_launch(void* const* d_in, const int* in_sizes, int n_in,
                              void* d_out, int out_size, void* d_ws, size_t ws_size,
                              hipStream_t stream) {
    const float* x  = (const float*)d_in[0];
    const int*   ei = (const int*)d_in[1];
    const float* W1 = (const float*)d_in[2];
    const float* b1 = (const float*)d_in[3];
    const float* W2 = (const float*)d_in[4];
    const float* b2 = (const float*)d_in[5];
    const float* Wc = (const float*)d_in[6];
    const float* bc = (const float*)d_in[7];
    float* out = (float*)d_out;

    const int N = in_sizes[0] / 128;
    const int E = in_sizes[1] / 2;
    const int* src = ei;
    const int* dst = ei + E;

    const int NBUCK = (N + BMASK) >> BSHIFT;   // <= 512
    const int NTILE = (E + TILE - 1) / TILE;

    char* ws = (char*)d_ws;
    size_t off = 0;
    auto alloc = [&](size_t elems) {
        void* p = ws + off;
        off += ((elems * 4 + 1023) & ~(size_t)1023);
        return p;
    };
    float* dinv   = (float*)alloc(N);
    int*   bcnt   = (int*)alloc(NBUCK_MAX);
    int*   bbase  = (int*)alloc(NBUCK_MAX + 1);
    int*   gcur   = (int*)alloc(NBUCK_MAX);
    int*   binned = (int*)alloc(E);
    float* hs     = (float*)alloc((size_t)N * 64);
    float* act    = (float*)alloc((size_t)N * 64);

    hipMemsetAsync(bcnt, 0, sizeof(int) * NBUCK_MAX, stream);

    k_hist<<<512, 256, 0, stream>>>(dst, bcnt, E);
    k_scanb<<<1, NBUCK_MAX, 0, stream>>>(bcnt, bbase, gcur, E);
    k_binA<<<NTILE, 256, 0, stream>>>(src, dst, gcur, binned, E);
    k_nodedeg<<<NBUCK, 256, 0, stream>>>(bbase, binned, dinv, N);

    // Layer 1: 128 -> 64
    k_gemm<128, 64><<<(N + 255) / 256, 256, 0, stream>>>(x, W1, dinv, hs, N);
    k_aggf64<<<NBUCK, 512, 0, stream>>>(bbase, binned, hs, dinv, b1, act, N);

    // Layer 2: 64 -> 32
    k_gemm<64, 32><<<(N + 255) / 256, 256, 0, stream>>>(act, W2, dinv, hs, N);
    k_aggf32<<<NBUCK, 512, 0, stream>>>(bbase, binned, hs, dinv, b2, act, N);

    // Classifier + log_softmax
    k_classifier<<<(N + 255) / 256, 256, 0, stream>>>(act, Wc, bc, out, N);
}

// Round 5
// 429.592 us; speedup vs baseline: 5.4859x; 5.4859x over previous
//
#include <hip/hip_runtime.h>

// GCN pipeline (R5):
//   k_hist:   per-bucket(256 dst nodes) edge counts, LDS hist
//   k_scanb:  exclusive scan -> bbase[], gcur[]
//   k_binA:   tile-wise LDS counting sort by bucket -> binned[] (src|dstlo<<17),
//             contiguous per-bucket dumps (dense writes in space AND time)
//   k_rowptr: per-bucket dstlo hist + scan -> rowptr[], dinv[]
//   k_bucketsort: per-bucket -> csr[] (writes confined to L2-resident region)
//   k_gemm:   hsb = pack_bf16((X @ W) * dinv[row])  (W in LDS, thread-per-row)
//   k_agg64n/k_agg32n: wave-per-node bf16 gather, 2/4 edges per load, fp32 acc
//   k_classifier: 32->10 + log_softmax

#define BSHIFT 8
#define BMASK 255
#define NBUCK_MAX 512
#define TILE 4096
#define EPT 16             // TILE / 256

__device__ __forceinline__ unsigned pack_bf16(float lo, float hi) {
    unsigned ul = __float_as_uint(lo);
    ul = (ul + 0x7FFFu + ((ul >> 16) & 1u)) >> 16;
    unsigned uh = __float_as_uint(hi);
    uh = ((uh + 0x7FFFu + ((uh >> 16) & 1u)) >> 16) << 16;
    return ul | uh;
}

__global__ void k_hist(const int* __restrict__ dst, int* __restrict__ bcnt, int E) {
    __shared__ int h[NBUCK_MAX];
    for (int i = threadIdx.x; i < NBUCK_MAX; i += blockDim.x) h[i] = 0;
    __syncthreads();
    for (int e = blockIdx.x * blockDim.x + threadIdx.x; e < E; e += gridDim.x * blockDim.x)
        atomicAdd(&h[dst[e] >> BSHIFT], 1);
    __syncthreads();
    for (int i = threadIdx.x; i < NBUCK_MAX; i += blockDim.x)
        if (h[i]) atomicAdd(&bcnt[i], h[i]);
}

__global__ void k_scanb(const int* __restrict__ bcnt, int* __restrict__ bbase,
                        int* __restrict__ gcur, int E) {
    __shared__ int s[NBUCK_MAX];
    int t = threadIdx.x;
    int v = bcnt[t];
    s[t] = v;
    __syncthreads();
    for (int o = 1; o < NBUCK_MAX; o <<= 1) {
        int u = (t >= o) ? s[t - o] : 0;
        __syncthreads();
        s[t] += u;
        __syncthreads();
    }
    int ex = s[t] - v;
    bbase[t] = ex;
    gcur[t] = ex;
    if (t == NBUCK_MAX - 1) bbase[NBUCK_MAX] = E;
}

// Tile-wise LDS counting sort by bucket; dump contiguous per-bucket runs.
__global__ __launch_bounds__(256) void k_binA(const int* __restrict__ src,
                                              const int* __restrict__ dst,
                                              int* __restrict__ gcur,
                                              int* __restrict__ binned, int E) {
    __shared__ int hist[NBUCK_MAX];
    __shared__ int lbase[NBUCK_MAX];
    __shared__ int gdelta[NBUCK_MAX];
    __shared__ int cnt2[NBUCK_MAX];
    __shared__ int scanb[256];
    __shared__ int stage[TILE];
    __shared__ unsigned short sbucket[TILE];

    int t = threadIdx.x;
    for (int i = t; i < NBUCK_MAX; i += 256) { hist[i] = 0; cnt2[i] = 0; }
    __syncthreads();

    int tileStart = blockIdx.x * TILE;
    int cntTile = min(TILE, E - tileStart);

    int vals[EPT];
    int bks[EPT];
#pragma unroll
    for (int i = 0; i < EPT; i++) {
        int e = tileStart + t + i * 256;
        if (e < E) {
            int s = src[e], d = dst[e];
            vals[i] = s | ((d & BMASK) << 17);
            bks[i] = d >> BSHIFT;
            atomicAdd(&hist[bks[i]], 1);
        } else bks[i] = -1;
    }
    __syncthreads();

    // exclusive scan of hist[512] with 256 threads (pairs)
    int a0 = hist[2 * t], a1 = hist[2 * t + 1];
    int ts = a0 + a1;
    scanb[t] = ts;
    __syncthreads();
    for (int o = 1; o < 256; o <<= 1) {
        int u = (t >= o) ? scanb[t - o] : 0;
        __syncthreads();
        scanb[t] += u;
        __syncthreads();
    }
    int ex = scanb[t] - ts;
    lbase[2 * t] = ex;
    lbase[2 * t + 1] = ex + a0;
    __syncthreads();

    for (int b = t; b < NBUCK_MAX; b += 256) {
        int c = hist[b];
        int g = c ? atomicAdd(&gcur[b], c) : 0;
        gdelta[b] = g - lbase[b];
    }
#pragma unroll
    for (int i = 0; i < EPT; i++) {
        if (bks[i] >= 0) {
            int r = atomicAdd(&cnt2[bks[i]], 1);
            int slot = lbase[bks[i]] + r;
            stage[slot] = vals[i];
            sbucket[slot] = (unsigned short)bks[i];
        }
    }
    __syncthreads();
    for (int i = t; i < cntTile; i += 256) {
        int b = sbucket[i];
        binned[gdelta[b] + i] = stage[i];
    }
}

// Per-bucket: dstlo hist -> rowptr (bbase[b] + local exclusive scan), dinv.
__global__ void k_rowptr(const int* __restrict__ bbase, const int* __restrict__ binned,
                         int* __restrict__ rowptr, float* __restrict__ dinv, int n, int E) {
    __shared__ int cnt[256];
    __shared__ int sc[256];
    int b = blockIdx.x, t = threadIdx.x;
    cnt[t] = 0;
    __syncthreads();
    int beg = bbase[b], end = bbase[b + 1];
    for (int i = beg + t; i < end; i += 256)
        atomicAdd(&cnt[(binned[i] >> 17) & BMASK], 1);
    __syncthreads();
    int v = cnt[t];
    sc[t] = v;
    __syncthreads();
    for (int o = 1; o < 256; o <<= 1) {
        int u = (t >= o) ? sc[t - o] : 0;
        __syncthreads();
        sc[t] += u;
        __syncthreads();
    }
    int g = (b << BSHIFT) + t;
    if (g < n) {
        rowptr[g] = beg + sc[t] - v;
        dinv[g] = rsqrtf((float)v + 1.0f);
        if (g == n - 1) rowptr[n] = E;
    }
}

// Per-bucket counting sort: csr[rowptr[d]+k] = src (writes inside dense region).
__global__ void k_bucketsort(const int* __restrict__ bbase, const int* __restrict__ rowptr,
                             const int* __restrict__ binned, int* __restrict__ csr, int n) {
    __shared__ int rpl[256];
    __shared__ int lcur[256];
    int b = blockIdx.x, t = threadIdx.x;
    int lo = b << BSHIFT;
    int g = lo + t;
    rpl[t] = (g < n) ? rowptr[g] : 0;
    lcur[t] = 0;
    __syncthreads();
    int beg = bbase[b], end = bbase[b + 1];
    for (int i = beg + t; i < end; i += 256) {
        int v = binned[i];
        int ln = (v >> 17) & BMASK;
        int k = atomicAdd(&lcur[ln], 1);
        csr[rpl[ln] + k] = v & 0x1FFFF;
    }
}

// hsb[n, M/2 uints] = pack_bf16((X[n,K] @ W[K,M]) * dinv[row])
template<int K, int M>
__global__ void k_gemm(const float* __restrict__ X, const float* __restrict__ W,
                       const float* __restrict__ dinv, unsigned* __restrict__ hsb, int n) {
    __shared__ float Ws[K * M];
    for (int i = threadIdx.x; i < K * M; i += blockDim.x) Ws[i] = W[i];
    __syncthreads();
    int r = blockIdx.x * blockDim.x + threadIdx.x;
    if (r >= n) return;
    float acc[M];
#pragma unroll
    for (int j = 0; j < M; j++) acc[j] = 0.f;
    const float* xr = X + (size_t)r * K;
    for (int k = 0; k < K; k += 4) {
        float4 xv = *(const float4*)(xr + k);
#pragma unroll
        for (int j = 0; j < M; j++) {
            acc[j] += xv.x * Ws[(k + 0) * M + j];
            acc[j] += xv.y * Ws[(k + 1) * M + j];
            acc[j] += xv.z * Ws[(k + 2) * M + j];
            acc[j] += xv.w * Ws[(k + 3) * M + j];
        }
    }
    float di = dinv[r];
    unsigned* hr = hsb + (size_t)r * (M / 2);
#pragma unroll
    for (int j = 0; j < M / 2; j++)
        hr[j] = pack_bf16(acc[2 * j] * di, acc[2 * j + 1] * di);
}

// Wave per node, F=64 bf16: half-wave per edge (2 edges/load), 2 feats/lane.
__global__ void k_agg64n(const int* __restrict__ rowptr, const int* __restrict__ csr,
                         const unsigned* __restrict__ hsb, const float* __restrict__ dinv,
                         const float* __restrict__ bv, float* __restrict__ out, int n) {
    int d = (blockIdx.x * blockDim.x + threadIdx.x) >> 6;
    if (d >= n) return;
    int lane = threadIdx.x & 63;
    int half = lane >> 5, l5 = lane & 31;
    int beg = rowptr[d], end = rowptr[d + 1];
    float di = dinv[d];
    float acc0 = 0.f, acc1 = 0.f;
    int base = beg;
    for (; base + 4 <= end; base += 4) {
        int sA = csr[base + half];
        int sB = csr[base + 2 + half];
        unsigned wA = hsb[(size_t)sA * 32 + l5];
        unsigned wB = hsb[(size_t)sB * 32 + l5];
        acc0 += __uint_as_float(wA << 16);
        acc1 += __uint_as_float(wA & 0xFFFF0000u);
        acc0 += __uint_as_float(wB << 16);
        acc1 += __uint_as_float(wB & 0xFFFF0000u);
    }
    for (int j = base + half; j < end; j += 2) {
        unsigned w = hsb[(size_t)csr[j] * 32 + l5];
        acc0 += __uint_as_float(w << 16);
        acc1 += __uint_as_float(w & 0xFFFF0000u);
    }
    acc0 += __shfl_xor(acc0, 32, 64);
    acc1 += __shfl_xor(acc1, 32, 64);
    if (half == 0) {
        unsigned ws = hsb[(size_t)d * 32 + l5];
        acc0 += __uint_as_float(ws << 16);
        acc1 += __uint_as_float(ws & 0xFFFF0000u);
        float v0 = fmaxf(acc0 * di + bv[2 * l5], 0.f);
        float v1 = fmaxf(acc1 * di + bv[2 * l5 + 1], 0.f);
        *(float2*)(out + (size_t)d * 64 + 2 * l5) = make_float2(v0, v1);
    }
}

// Wave per node, F=32 bf16: quarter-wave per edge (4 edges/load), 2 feats/lane.
__global__ void k_agg32n(const int* __restrict__ rowptr, const int* __restrict__ csr,
                         const unsigned* __restrict__ hsb, const float* __restrict__ dinv,
                         const float* __restrict__ bv, float* __restrict__ out, int n) {
    int d = (blockIdx.x * blockDim.x + threadIdx.x) >> 6;
    if (d >= n) return;
    int lane = threadIdx.x & 63;
    int quarter = lane >> 4, l4 = lane & 15;
    int beg = rowptr[d], end = rowptr[d + 1];
    float di = dinv[d];
    float acc0 = 0.f, acc1 = 0.f;
    int base = beg;
    for (; base + 8 <= end; base += 8) {
        int sA = csr[base + quarter];
        int sB = csr[base + 4 + quarter];
        unsigned wA = hsb[(size_t)sA * 16 + l4];
        unsigned wB = hsb[(size_t)sB * 16 + l4];
        acc0 += __uint_as_float(wA << 16);
        acc1 += __uint_as_float(wA & 0xFFFF0000u);
        acc0 += __uint_as_float(wB << 16);
        acc1 += __uint_as_float(wB & 0xFFFF0000u);
    }
    for (int j = base + quarter; j < end; j += 4) {
        unsigned w = hsb[(size_t)csr[j] * 16 + l4];
        acc0 += __uint_as_float(w << 16);
        acc1 += __uint_as_float(w & 0xFFFF0000u);
    }
    acc0 += __shfl_xor(acc0, 16, 64);
    acc1 += __shfl_xor(acc1, 16, 64);
    acc0 += __shfl_xor(acc0, 32, 64);
    acc1 += __shfl_xor(acc1, 32, 64);
    if (quarter == 0) {
        unsigned ws = hsb[(size_t)d * 16 + l4];
        acc0 += __uint_as_float(ws << 16);
        acc1 += __uint_as_float(ws & 0xFFFF0000u);
        float v0 = fmaxf(acc0 * di + bv[2 * l4], 0.f);
        float v1 = fmaxf(acc1 * di + bv[2 * l4 + 1], 0.f);
        *(float2*)(out + (size_t)d * 32 + 2 * l4) = make_float2(v0, v1);
    }
}

// logits = act2 @ Wc + bc; log_softmax
__global__ void k_classifier(const float* __restrict__ ACT, const float* __restrict__ Wc,
                             const float* __restrict__ bc, float* __restrict__ out, int n) {
    __shared__ float Wcs[32 * 10];
    __shared__ float bcs[10];
    for (int i = threadIdx.x; i < 320; i += blockDim.x) Wcs[i] = Wc[i];
    if (threadIdx.x < 10) bcs[threadIdx.x] = bc[threadIdx.x];
    __syncthreads();
    int r = blockIdx.x * blockDim.x + threadIdx.x;
    if (r >= n) return;
    const float* a = ACT + (size_t)r * 32;
    float logits[10];
#pragma unroll
    for (int c = 0; c < 10; c++) logits[c] = bcs[c];
#pragma unroll
    for (int k = 0; k < 32; k += 4) {
        float4 av = *(const float4*)(a + k);
#pragma unroll
        for (int c = 0; c < 10; c++) {
            logits[c] += av.x * Wcs[(k + 0) * 10 + c] + av.y * Wcs[(k + 1) * 10 + c]
                       + av.z * Wcs[(k + 2) * 10 + c] + av.w * Wcs[(k + 3) * 10 + c];
        }
    }
    float m = logits[0];
#pragma unroll
    for (int c = 1; c < 10; c++) m = fmaxf(m, logits[c]);
    float ssum = 0.f;
#pragma unroll
    for (int c = 0; c < 10; c++) ssum += __expf(logits[c] - m);
    float lse = m + __logf(ssum);
    float* o = out + (size_t)r * 10;
#pragma unroll
    for (int c = 0; c < 10; c++) o[c] = logits[c] - lse;
}

extern "C" void kernel_launch(void* const* d_in, const int* in_sizes, int n_in,
                              void* d_out, int out_size, void* d_ws, size_t ws_size,
                              hipStream_t stream) {
    const float* x  = (const float*)d_in[0];
    const int*   ei = (const int*)d_in[1];
    const float* W1 = (const float*)d_in[2];
    const float* b1 = (const float*)d_in[3];
    const float* W2 = (const float*)d_in[4];
    const float* b2 = (const float*)d_in[5];
    const float* Wc = (const float*)d_in[6];
    const float* bc = (const float*)d_in[7];
    float* out = (float*)d_out;

    const int N = in_sizes[0] / 128;
    const int E = in_sizes[1] / 2;
    const int* src = ei;
    const int* dst = ei + E;

    const int NBUCK = (N + BMASK) >> BSHIFT;   // <= 512
    const int NTILE = (E + TILE - 1) / TILE;

    char* ws = (char*)d_ws;
    size_t off = 0;
    auto alloc = [&](size_t elems) {
        void* p = ws + off;
        off += ((elems * 4 + 1023) & ~(size_t)1023);
        return p;
    };
    float*    dinv   = (float*)alloc(N);
    int*      bcnt   = (int*)alloc(NBUCK_MAX);
    int*      bbase  = (int*)alloc(NBUCK_MAX + 1);
    int*      gcur   = (int*)alloc(NBUCK_MAX);
    int*      rowptr = (int*)alloc(N + 1);
    int*      binned = (int*)alloc(E);
    int*      csr    = (int*)alloc(E);
    unsigned* hsb    = (unsigned*)alloc((size_t)N * 32);  // bf16x2: layer1 rows (32 u) / layer2 rows (16 u)
    float*    act    = (float*)alloc((size_t)N * 64);     // act1 (N*64) then act2 (N*32)

    hipMemsetAsync(bcnt, 0, sizeof(int) * NBUCK_MAX, stream);

    // CSR build
    k_hist<<<512, 256, 0, stream>>>(dst, bcnt, E);
    k_scanb<<<1, NBUCK_MAX, 0, stream>>>(bcnt, bbase, gcur, E);
    k_binA<<<NTILE, 256, 0, stream>>>(src, dst, gcur, binned, E);
    k_rowptr<<<NBUCK, 256, 0, stream>>>(bbase, binned, rowptr, dinv, N, E);
    k_bucketsort<<<NBUCK, 256, 0, stream>>>(bbase, rowptr, binned, csr, N);

    // Layer 1: 128 -> 64
    k_gemm<128, 64><<<(N + 255) / 256, 256, 0, stream>>>(x, W1, dinv, hsb, N);
    k_agg64n<<<(N * 64 + 255) / 256, 256, 0, stream>>>(rowptr, csr, hsb, dinv, b1, act, N);

    // Layer 2: 64 -> 32
    k_gemm<64, 32><<<(N + 255) / 256, 256, 0, stream>>>(act, W2, dinv, hsb, N);
    k_agg32n<<<(N * 64 + 255) / 256, 256, 0, stream>>>(rowptr, csr, hsb, dinv, b2, act, N);

    // Classifier + log_softmax
    k_classifier<<<(N + 255) / 256, 256, 0, stream>>>(act, Wc, bc, out, N);
}

// Round 6
// 376.661 us; speedup vs baseline: 6.2568x; 1.1405x over previous
//
#include <hip/hip_runtime.h>

// GCN pipeline (R6):
//   k_hist:    per-bucket(256 dst nodes) edge counts, LDS hist
//   k_scanb:   exclusive scan -> bbase[], gcur[]
//   k_binA:    tile-wise LDS counting sort by bucket -> binned[] (src|dstlo<<17)
//   k_sortcsr: per-bucket dstlo hist+scan -> rowptr, dinv; placement -> csr
//   k_gemm:    hsb = pack_bf16((X @ W) * dinv[row]); 4 rows/thread, wave-split cols
//   k_agg64n/k_agg32n: wave-per-node uint4 bf16 gather (8/16 rows per load instr)
//   k_classifier: 32->10 + log_softmax

#define BSHIFT 8
#define BMASK 255
#define NBUCK_MAX 512
#define TILE 4096
#define EPT 16             // TILE / 256

__device__ __forceinline__ unsigned pack_bf16(float lo, float hi) {
    unsigned ul = __float_as_uint(lo);
    ul = (ul + 0x7FFFu + ((ul >> 16) & 1u)) >> 16;
    unsigned uh = __float_as_uint(hi);
    uh = ((uh + 0x7FFFu + ((uh >> 16) & 1u)) >> 16) << 16;
    return ul | uh;
}

__global__ void k_hist(const int* __restrict__ dst, int* __restrict__ bcnt, int E) {
    __shared__ int h[NBUCK_MAX];
    for (int i = threadIdx.x; i < NBUCK_MAX; i += blockDim.x) h[i] = 0;
    __syncthreads();
    for (int e = blockIdx.x * blockDim.x + threadIdx.x; e < E; e += gridDim.x * blockDim.x)
        atomicAdd(&h[dst[e] >> BSHIFT], 1);
    __syncthreads();
    for (int i = threadIdx.x; i < NBUCK_MAX; i += blockDim.x)
        if (h[i]) atomicAdd(&bcnt[i], h[i]);
}

__global__ void k_scanb(const int* __restrict__ bcnt, int* __restrict__ bbase,
                        int* __restrict__ gcur, int E) {
    __shared__ int s[NBUCK_MAX];
    int t = threadIdx.x;
    int v = bcnt[t];
    s[t] = v;
    __syncthreads();
    for (int o = 1; o < NBUCK_MAX; o <<= 1) {
        int u = (t >= o) ? s[t - o] : 0;
        __syncthreads();
        s[t] += u;
        __syncthreads();
    }
    int ex = s[t] - v;
    bbase[t] = ex;
    gcur[t] = ex;
    if (t == NBUCK_MAX - 1) bbase[NBUCK_MAX] = E;
}

// Tile-wise LDS counting sort by bucket; dump contiguous per-bucket runs.
__global__ __launch_bounds__(256) void k_binA(const int* __restrict__ src,
                                              const int* __restrict__ dst,
                                              int* __restrict__ gcur,
                                              int* __restrict__ binned, int E) {
    __shared__ int hist[NBUCK_MAX];
    __shared__ int lbase[NBUCK_MAX];
    __shared__ int gdelta[NBUCK_MAX];
    __shared__ int cnt2[NBUCK_MAX];
    __shared__ int scanb[256];
    __shared__ int stage[TILE];
    __shared__ unsigned short sbucket[TILE];

    int t = threadIdx.x;
    for (int i = t; i < NBUCK_MAX; i += 256) { hist[i] = 0; cnt2[i] = 0; }
    __syncthreads();

    int tileStart = blockIdx.x * TILE;
    int cntTile = min(TILE, E - tileStart);

    int vals[EPT];
    int bks[EPT];
#pragma unroll
    for (int i = 0; i < EPT; i++) {
        int e = tileStart + t + i * 256;
        if (e < E) {
            int s = src[e], d = dst[e];
            vals[i] = s | ((d & BMASK) << 17);
            bks[i] = d >> BSHIFT;
            atomicAdd(&hist[bks[i]], 1);
        } else bks[i] = -1;
    }
    __syncthreads();

    int a0 = hist[2 * t], a1 = hist[2 * t + 1];
    int ts = a0 + a1;
    scanb[t] = ts;
    __syncthreads();
    for (int o = 1; o < 256; o <<= 1) {
        int u = (t >= o) ? scanb[t - o] : 0;
        __syncthreads();
        scanb[t] += u;
        __syncthreads();
    }
    int ex = scanb[t] - ts;
    lbase[2 * t] = ex;
    lbase[2 * t + 1] = ex + a0;
    __syncthreads();

    for (int b = t; b < NBUCK_MAX; b += 256) {
        int c = hist[b];
        int g = c ? atomicAdd(&gcur[b], c) : 0;
        gdelta[b] = g - lbase[b];
    }
#pragma unroll
    for (int i = 0; i < EPT; i++) {
        if (bks[i] >= 0) {
            int rr = atomicAdd(&cnt2[bks[i]], 1);
            int slot = lbase[bks[i]] + rr;
            stage[slot] = vals[i];
            sbucket[slot] = (unsigned short)bks[i];
        }
    }
    __syncthreads();
    for (int i = t; i < cntTile; i += 256) {
        int b = sbucket[i];
        binned[gdelta[b] + i] = stage[i];
    }
}

// Per-bucket: hist+scan -> rowptr, dinv; then placement -> csr.
__global__ void k_sortcsr(const int* __restrict__ bbase, const int* __restrict__ binned,
                          int* __restrict__ rowptr, float* __restrict__ dinv,
                          int* __restrict__ csr, int n, int E) {
    __shared__ int cnt[256];
    __shared__ int sc[256];
    __shared__ int rpl[256];
    __shared__ int lcur[256];
    int b = blockIdx.x, t = threadIdx.x;
    cnt[t] = 0; lcur[t] = 0;
    __syncthreads();
    int beg = bbase[b], end = bbase[b + 1];
    for (int i = beg + t; i < end; i += 256)
        atomicAdd(&cnt[(binned[i] >> 17) & BMASK], 1);
    __syncthreads();
    int v = cnt[t];
    sc[t] = v;
    __syncthreads();
    for (int o = 1; o < 256; o <<= 1) {
        int u = (t >= o) ? sc[t - o] : 0;
        __syncthreads();
        sc[t] += u;
        __syncthreads();
    }
    int rp = beg + sc[t] - v;
    rpl[t] = rp;
    int g = (b << BSHIFT) + t;
    if (g < n) {
        rowptr[g] = rp;
        dinv[g] = rsqrtf((float)v + 1.0f);
        if (g == n - 1) rowptr[n] = E;
    }
    __syncthreads();
    for (int i = beg + t; i < end; i += 256) {
        int vv = binned[i];
        int ln = (vv >> 17) & BMASK;
        int k = atomicAdd(&lcur[ln], 1);
        csr[rpl[ln] + k] = vv & 0x1FFFF;
    }
}

// hsb = pack_bf16((X @ W) * dinv[row]); block = 256 rows; thread = 4 rows;
// wave w owns cols [w*M/4, (w+1)*M/4) -> each Ws float4 feeds 16 FMAs.
template<int K, int M>
__global__ __launch_bounds__(256) void k_gemm(const float* __restrict__ X,
                                              const float* __restrict__ W,
                                              const float* __restrict__ dinv,
                                              unsigned* __restrict__ hsb, int n) {
    constexpr int MW = M / 4;       // cols per wave
    __shared__ float Ws[K * M];
    for (int i = threadIdx.x; i < K * M; i += 256) Ws[i] = W[i];
    __syncthreads();
    int w = threadIdx.x >> 6, lane = threadIdx.x & 63;
    int wo = w * MW;
    int r0 = blockIdx.x * 256 + lane;
    float acc[4][MW];
#pragma unroll
    for (int i = 0; i < 4; i++)
#pragma unroll
        for (int j = 0; j < MW; j++) acc[i][j] = 0.f;

    for (int k = 0; k < K; k += 4) {
        float4 xv[4];
#pragma unroll
        for (int i = 0; i < 4; i++) {
            int rr = r0 + 64 * i;
            xv[i] = (rr < n) ? *(const float4*)(X + (size_t)rr * K + k)
                             : make_float4(0.f, 0.f, 0.f, 0.f);
        }
#pragma unroll
        for (int kk = 0; kk < 4; kk++) {
#pragma unroll
            for (int j = 0; j < MW; j += 4) {
                float4 wv = *(const float4*)&Ws[(k + kk) * M + wo + j];
#pragma unroll
                for (int i = 0; i < 4; i++) {
                    float xs = (kk == 0) ? xv[i].x : (kk == 1) ? xv[i].y
                             : (kk == 2) ? xv[i].z : xv[i].w;
                    acc[i][j + 0] += xs * wv.x;
                    acc[i][j + 1] += xs * wv.y;
                    acc[i][j + 2] += xs * wv.z;
                    acc[i][j + 3] += xs * wv.w;
                }
            }
        }
    }
#pragma unroll
    for (int i = 0; i < 4; i++) {
        int rr = r0 + 64 * i;
        if (rr < n) {
            float di = dinv[rr];
            unsigned p[MW / 2];
#pragma unroll
            for (int jj = 0; jj < MW / 2; jj++)
                p[jj] = pack_bf16(acc[i][2 * jj] * di, acc[i][2 * jj + 1] * di);
            unsigned* hr = hsb + (size_t)rr * (M / 2) + wo / 2;
#pragma unroll
            for (int jj = 0; jj < MW / 2; jj += 4)
                *(uint4*)(hr + jj) = make_uint4(p[jj], p[jj + 1], p[jj + 2], p[jj + 3]);
        }
    }
}

// Wave per node, F=64: 8 lanes/row (uint4 = 8 bf16 feats), 16 rows per load pair.
__global__ void k_agg64n(const int* __restrict__ rowptr, const int* __restrict__ csr,
                         const uint4* __restrict__ hsb, const float* __restrict__ dinv,
                         const float* __restrict__ bv, float* __restrict__ out, int n) {
    __shared__ float bs[64];
    if (threadIdx.x < 64) bs[threadIdx.x] = bv[threadIdx.x];
    __syncthreads();
    int d = (blockIdx.x * blockDim.x + threadIdx.x) >> 6;
    if (d >= n) return;
    int lane = threadIdx.x & 63;
    int q = lane >> 3;      // edge slot 0..7
    int r = lane & 7;       // feat chunk: feats 8r..8r+7
    int beg = rowptr[d], end = rowptr[d + 1];
    float acc[8];
#pragma unroll
    for (int i = 0; i < 8; i++) acc[i] = 0.f;
    int base = beg;
    for (; base + 16 <= end; base += 16) {
        int sA = csr[base + q];
        int sB = csr[base + 8 + q];
        uint4 wA = hsb[(size_t)sA * 8 + r];
        uint4 wB = hsb[(size_t)sB * 8 + r];
        acc[0] += __uint_as_float(wA.x << 16);  acc[1] += __uint_as_float(wA.x & 0xFFFF0000u);
        acc[2] += __uint_as_float(wA.y << 16);  acc[3] += __uint_as_float(wA.y & 0xFFFF0000u);
        acc[4] += __uint_as_float(wA.z << 16);  acc[5] += __uint_as_float(wA.z & 0xFFFF0000u);
        acc[6] += __uint_as_float(wA.w << 16);  acc[7] += __uint_as_float(wA.w & 0xFFFF0000u);
        acc[0] += __uint_as_float(wB.x << 16);  acc[1] += __uint_as_float(wB.x & 0xFFFF0000u);
        acc[2] += __uint_as_float(wB.y << 16);  acc[3] += __uint_as_float(wB.y & 0xFFFF0000u);
        acc[4] += __uint_as_float(wB.z << 16);  acc[5] += __uint_as_float(wB.z & 0xFFFF0000u);
        acc[6] += __uint_as_float(wB.w << 16);  acc[7] += __uint_as_float(wB.w & 0xFFFF0000u);
    }
    if (base + q < end) {
        uint4 w = hsb[(size_t)csr[base + q] * 8 + r];
        acc[0] += __uint_as_float(w.x << 16);  acc[1] += __uint_as_float(w.x & 0xFFFF0000u);
        acc[2] += __uint_as_float(w.y << 16);  acc[3] += __uint_as_float(w.y & 0xFFFF0000u);
        acc[4] += __uint_as_float(w.z << 16);  acc[5] += __uint_as_float(w.z & 0xFFFF0000u);
        acc[6] += __uint_as_float(w.w << 16);  acc[7] += __uint_as_float(w.w & 0xFFFF0000u);
    }
    if (base + 8 + q < end) {
        uint4 w = hsb[(size_t)csr[base + 8 + q] * 8 + r];
        acc[0] += __uint_as_float(w.x << 16);  acc[1] += __uint_as_float(w.x & 0xFFFF0000u);
        acc[2] += __uint_as_float(w.y << 16);  acc[3] += __uint_as_float(w.y & 0xFFFF0000u);
        acc[4] += __uint_as_float(w.z << 16);  acc[5] += __uint_as_float(w.z & 0xFFFF0000u);
        acc[6] += __uint_as_float(w.w << 16);  acc[7] += __uint_as_float(w.w & 0xFFFF0000u);
    }
#pragma unroll
    for (int i = 0; i < 8; i++) {
        acc[i] += __shfl_xor(acc[i], 8, 64);
        acc[i] += __shfl_xor(acc[i], 16, 64);
        acc[i] += __shfl_xor(acc[i], 32, 64);
    }
    // self loop (after reduce: add once, replicated)
    uint4 ws = hsb[(size_t)d * 8 + r];
    acc[0] += __uint_as_float(ws.x << 16);  acc[1] += __uint_as_float(ws.x & 0xFFFF0000u);
    acc[2] += __uint_as_float(ws.y << 16);  acc[3] += __uint_as_float(ws.y & 0xFFFF0000u);
    acc[4] += __uint_as_float(ws.z << 16);  acc[5] += __uint_as_float(ws.z & 0xFFFF0000u);
    acc[6] += __uint_as_float(ws.w << 16);  acc[7] += __uint_as_float(ws.w & 0xFFFF0000u);
    if (q == 0) {
        float di = dinv[d];
        float v[8];
#pragma unroll
        for (int i = 0; i < 8; i++) v[i] = fmaxf(acc[i] * di + bs[8 * r + i], 0.f);
        float* o = out + (size_t)d * 64 + 8 * r;
        *(float4*)(o + 0) = make_float4(v[0], v[1], v[2], v[3]);
        *(float4*)(o + 4) = make_float4(v[4], v[5], v[6], v[7]);
    }
}

// Wave per node, F=32: 4 lanes/row, 32 rows per load pair.
__global__ void k_agg32n(const int* __restrict__ rowptr, const int* __restrict__ csr,
                         const uint4* __restrict__ hsb, const float* __restrict__ dinv,
                         const float* __restrict__ bv, float* __restrict__ out, int n) {
    __shared__ float bs[32];
    if (threadIdx.x < 32) bs[threadIdx.x] = bv[threadIdx.x];
    __syncthreads();
    int d = (blockIdx.x * blockDim.x + threadIdx.x) >> 6;
    if (d >= n) return;
    int lane = threadIdx.x & 63;
    int q = lane >> 2;      // edge slot 0..15
    int r = lane & 3;       // feat chunk: feats 8r..8r+7
    int beg = rowptr[d], end = rowptr[d + 1];
    float acc[8];
#pragma unroll
    for (int i = 0; i < 8; i++) acc[i] = 0.f;
    int base = beg;
    for (; base + 32 <= end; base += 32) {
        int sA = csr[base + q];
        int sB = csr[base + 16 + q];
        uint4 wA = hsb[(size_t)sA * 4 + r];
        uint4 wB = hsb[(size_t)sB * 4 + r];
        acc[0] += __uint_as_float(wA.x << 16);  acc[1] += __uint_as_float(wA.x & 0xFFFF0000u);
        acc[2] += __uint_as_float(wA.y << 16);  acc[3] += __uint_as_float(wA.y & 0xFFFF0000u);
        acc[4] += __uint_as_float(wA.z << 16);  acc[5] += __uint_as_float(wA.z & 0xFFFF0000u);
        acc[6] += __uint_as_float(wA.w << 16);  acc[7] += __uint_as_float(wA.w & 0xFFFF0000u);
        acc[0] += __uint_as_float(wB.x << 16);  acc[1] += __uint_as_float(wB.x & 0xFFFF0000u);
        acc[2] += __uint_as_float(wB.y << 16);  acc[3] += __uint_as_float(wB.y & 0xFFFF0000u);
        acc[4] += __uint_as_float(wB.z << 16);  acc[5] += __uint_as_float(wB.z & 0xFFFF0000u);
        acc[6] += __uint_as_float(wB.w << 16);  acc[7] += __uint_as_float(wB.w & 0xFFFF0000u);
    }
    if (base + q < end) {
        uint4 w = hsb[(size_t)csr[base + q] * 4 + r];
        acc[0] += __uint_as_float(w.x << 16);  acc[1] += __uint_as_float(w.x & 0xFFFF0000u);
        acc[2] += __uint_as_float(w.y << 16);  acc[3] += __uint_as_float(w.y & 0xFFFF0000u);
        acc[4] += __uint_as_float(w.z << 16);  acc[5] += __uint_as_float(w.z & 0xFFFF0000u);
        acc[6] += __uint_as_float(w.w << 16);  acc[7] += __uint_as_float(w.w & 0xFFFF0000u);
    }
    if (base + 16 + q < end) {
        uint4 w = hsb[(size_t)csr[base + 16 + q] * 4 + r];
        acc[0] += __uint_as_float(w.x << 16);  acc[1] += __uint_as_float(w.x & 0xFFFF0000u);
        acc[2] += __uint_as_float(w.y << 16);  acc[3] += __uint_as_float(w.y & 0xFFFF0000u);
        acc[4] += __uint_as_float(w.z << 16);  acc[5] += __uint_as_float(w.z & 0xFFFF0000u);
        acc[6] += __uint_as_float(w.w << 16);  acc[7] += __uint_as_float(w.w & 0xFFFF0000u);
    }
#pragma unroll
    for (int i = 0; i < 8; i++) {
        acc[i] += __shfl_xor(acc[i], 4, 64);
        acc[i] += __shfl_xor(acc[i], 8, 64);
        acc[i] += __shfl_xor(acc[i], 16, 64);
        acc[i] += __shfl_xor(acc[i], 32, 64);
    }
    uint4 ws = hsb[(size_t)d * 4 + r];
    acc[0] += __uint_as_float(ws.x << 16);  acc[1] += __uint_as_float(ws.x & 0xFFFF0000u);
    acc[2] += __uint_as_float(ws.y << 16);  acc[3] += __uint_as_float(ws.y & 0xFFFF0000u);
    acc[4] += __uint_as_float(ws.z << 16);  acc[5] += __uint_as_float(ws.z & 0xFFFF0000u);
    acc[6] += __uint_as_float(ws.w << 16);  acc[7] += __uint_as_float(ws.w & 0xFFFF0000u);
    if (q == 0) {
        float di = dinv[d];
        float v[8];
#pragma unroll
        for (int i = 0; i < 8; i++) v[i] = fmaxf(acc[i] * di + bs[8 * r + i], 0.f);
        float* o = out + (size_t)d * 32 + 8 * r;
        *(float4*)(o + 0) = make_float4(v[0], v[1], v[2], v[3]);
        *(float4*)(o + 4) = make_float4(v[4], v[5], v[6], v[7]);
    }
}

// logits = act2 @ Wc + bc; log_softmax
__global__ void k_classifier(const float* __restrict__ ACT, const float* __restrict__ Wc,
                             const float* __restrict__ bc, float* __restrict__ out, int n) {
    __shared__ float Wcs[32 * 10];
    __shared__ float bcs[10];
    for (int i = threadIdx.x; i < 320; i += blockDim.x) Wcs[i] = Wc[i];
    if (threadIdx.x < 10) bcs[threadIdx.x] = bc[threadIdx.x];
    __syncthreads();
    int r = blockIdx.x * blockDim.x + threadIdx.x;
    if (r >= n) return;
    const float* a = ACT + (size_t)r * 32;
    float logits[10];
#pragma unroll
    for (int c = 0; c < 10; c++) logits[c] = bcs[c];
#pragma unroll
    for (int k = 0; k < 32; k += 4) {
        float4 av = *(const float4*)(a + k);
#pragma unroll
        for (int c = 0; c < 10; c++) {
            logits[c] += av.x * Wcs[(k + 0) * 10 + c] + av.y * Wcs[(k + 1) * 10 + c]
                       + av.z * Wcs[(k + 2) * 10 + c] + av.w * Wcs[(k + 3) * 10 + c];
        }
    }
    float m = logits[0];
#pragma unroll
    for (int c = 1; c < 10; c++) m = fmaxf(m, logits[c]);
    float ssum = 0.f;
#pragma unroll
    for (int c = 0; c < 10; c++) ssum += __expf(logits[c] - m);
    float lse = m + __logf(ssum);
    float* o = out + (size_t)r * 10;
#pragma unroll
    for (int c = 0; c < 10; c++) o[c] = logits[c] - lse;
}

extern "C" void kernel_launch(void* const* d_in, const int* in_sizes, int n_in,
                              void* d_out, int out_size, void* d_ws, size_t ws_size,
                              hipStream_t stream) {
    const float* x  = (const float*)d_in[0];
    const int*   ei = (const int*)d_in[1];
    const float* W1 = (const float*)d_in[2];
    const float* b1 = (const float*)d_in[3];
    const float* W2 = (const float*)d_in[4];
    const float* b2 = (const float*)d_in[5];
    const float* Wc = (const float*)d_in[6];
    const float* bc = (const float*)d_in[7];
    float* out = (float*)d_out;

    const int N = in_sizes[0] / 128;
    const int E = in_sizes[1] / 2;
    const int* src = ei;
    const int* dst = ei + E;

    const int NBUCK = (N + BMASK) >> BSHIFT;   // <= 512
    const int NTILE = (E + TILE - 1) / TILE;

    char* ws = (char*)d_ws;
    size_t off = 0;
    auto alloc = [&](size_t elems) {
        void* p = ws + off;
        off += ((elems * 4 + 1023) & ~(size_t)1023);
        return p;
    };
    float*    dinv   = (float*)alloc(N);
    int*      bcnt   = (int*)alloc(NBUCK_MAX);
    int*      bbase  = (int*)alloc(NBUCK_MAX + 1);
    int*      gcur   = (int*)alloc(NBUCK_MAX);
    int*      rowptr = (int*)alloc(N + 1);
    int*      binned = (int*)alloc(E);
    int*      csr    = (int*)alloc(E);
    unsigned* hsb    = (unsigned*)alloc((size_t)N * 32);  // packed bf16 rows
    float*    act    = (float*)alloc((size_t)N * 64);     // act1 (N*64) then act2 (N*32)

    hipMemsetAsync(bcnt, 0, sizeof(int) * NBUCK_MAX, stream);

    // CSR build
    k_hist<<<512, 256, 0, stream>>>(dst, bcnt, E);
    k_scanb<<<1, NBUCK_MAX, 0, stream>>>(bcnt, bbase, gcur, E);
    k_binA<<<NTILE, 256, 0, stream>>>(src, dst, gcur, binned, E);
    k_sortcsr<<<NBUCK, 256, 0, stream>>>(bbase, binned, rowptr, dinv, csr, N, E);

    // Layer 1: 128 -> 64
    k_gemm<128, 64><<<(N + 255) / 256, 256, 0, stream>>>(x, W1, dinv, hsb, N);
    k_agg64n<<<(N * 64 + 255) / 256, 256, 0, stream>>>(rowptr, csr, (const uint4*)hsb,
                                                       dinv, b1, act, N);

    // Layer 2: 64 -> 32
    k_gemm<64, 32><<<(N + 255) / 256, 256, 0, stream>>>(act, W2, dinv, hsb, N);
    k_agg32n<<<(N * 64 + 255) / 256, 256, 0, stream>>>(rowptr, csr, (const uint4*)hsb,
                                                       dinv, b2, act, N);

    // Classifier + log_softmax
    k_classifier<<<(N + 255) / 256, 256, 0, stream>>>(act, Wc, bc, out, N);
}